// Round 1
// baseline (401.134 us; speedup 1.0000x reference)
//
#include <hip/hip_runtime.h>
#include <hip/hip_bf16.h>

typedef _Float16 f16x8 __attribute__((ext_vector_type(8)));
typedef _Float16 f16x4 __attribute__((ext_vector_type(4)));
typedef float f32x4 __attribute__((ext_vector_type(4)));

#define MFMA32(a, b, c) __builtin_amdgcn_mfma_f32_16x16x32_f16(a, b, c, 0, 0, 0)
#define MFMA16(a, b, c) __builtin_amdgcn_mfma_f32_16x16x16f16(a, b, c, 0, 0, 0)

// async global->LDS, 16B per lane, linear dest (wave base + lane*16)
#define GLOAD_LDS16(g, l)                                         \
  __builtin_amdgcn_global_load_lds(                               \
      (const __attribute__((address_space(1))) void*)(g),         \
      (__attribute__((address_space(3))) void*)(l), 16, 0, 0)

// ---------------------------------------------------------------------------
// Kernel 0a: batched transpose + f32->f16 convert.  in: [R][C] f32 per batch,
// out: [C][R] f16 per batch.  Output-coalesced.
// ---------------------------------------------------------------------------
__global__ __launch_bounds__(256) void tconv_kernel(
    const float* __restrict__ in, _Float16* __restrict__ out, int R, int C) {
  size_t bat = (size_t)blockIdx.y * R * C;
  int o = blockIdx.x * 256 + threadIdx.x;
  if (o < R * C) {
    int c = o / R, r = o - c * R;
    out[bat + o] = (_Float16)in[bat + (size_t)r * C + c];
  }
}

// ---------------------------------------------------------------------------
// Kernel 0b: straight f32 -> f16 convert, 8 elts/thread.
// ---------------------------------------------------------------------------
__global__ __launch_bounds__(256) void cvt16_kernel(
    const float* __restrict__ in, _Float16* __restrict__ out, int n) {
  int i = (blockIdx.x * 256 + threadIdx.x) * 8;
  if (i < n) {
    float4 a = *(const float4*)(in + i);
    float4 b = *(const float4*)(in + i + 4);
    f16x8 cv;
    cv[0] = (_Float16)a.x; cv[1] = (_Float16)a.y;
    cv[2] = (_Float16)a.z; cv[3] = (_Float16)a.w;
    cv[4] = (_Float16)b.x; cv[5] = (_Float16)b.y;
    cv[6] = (_Float16)b.z; cv[7] = (_Float16)b.w;
    *(f16x8*)(out + i) = cv;
  }
}

// ---------------------------------------------------------------------------
// Kernel 1: fused QKV projection as ONE GEMM.
// C[m][n] = sum_e zh[m][e] * Ut[n][e],  M=16384, N=2304, K=768.
// NEW: global_load_lds staging into unpadded [128][64] f16 LDS with XOR
// swizzle (phys_byte = row*128 + (col_byte ^ ((row&7)<<4))), applied on BOTH
// the per-lane global source (inverse) and the ds_read side -> linear LDS
// dest for global_load_lds, 2-way (free) bank access on fragment reads.
// XCD-chunked block swizzle: 2304 = 8 XCD * 288, m-tile fastest in chunk.
// ---------------------------------------------------------------------------
__global__ __launch_bounds__(256) void qkv_gemm_kernel(
    const _Float16* __restrict__ zh, const _Float16* __restrict__ Ut,
    _Float16* __restrict__ Qf, _Float16* __restrict__ Kf,
    _Float16* __restrict__ Vt) {
  __shared__ _Float16 As[128 * 64];
  __shared__ _Float16 Bs[128 * 64];

  const int tid = threadIdx.x;
  const int wv = tid >> 6, lane = tid & 63, quad = lane >> 4, l16 = lane & 15;

  const int flat = blockIdx.y * 128 + blockIdx.x;
  const int swz = (flat & 7) * 288 + (flat >> 3);
  const int m0 = (swz & 127) * 128;
  const int by = swz >> 7;
  const int n0 = by * 128;

  // staging: lane covers row (8-row group + lane>>3), 16B chunk (lane&7),
  // global col pre-swizzled so linear LDS ends up XOR-swizzled
  const int srow = lane >> 3;
  const int scol = ((lane & 7) ^ srow) << 3;  // f16 units
  const _Float16* Ag = zh + (size_t)(m0 + srow) * 768 + scol;
  const _Float16* Bg = Ut + (size_t)(n0 + srow) * 768 + scol;

  const int cbq = quad * 16;  // byte col of this lane's fragment within row

  f32x4 acc[2][8] = {};

  for (int k0 = 0; k0 < 768; k0 += 64) {
    __syncthreads();
#pragma unroll
    for (int i = 0; i < 4; ++i) {
      const int rb = (i * 4 + wv) * 8;
      GLOAD_LDS16(Ag + (size_t)rb * 768 + k0, (char*)As + rb * 128);
      GLOAD_LDS16(Bg + (size_t)rb * 768 + k0, (char*)Bs + rb * 128);
    }
    __syncthreads();
#pragma unroll
    for (int ks = 0; ks < 2; ++ks) {
      f16x8 af[2], bfr[8];
#pragma unroll
      for (int rt = 0; rt < 2; ++rt) {
        const int r = wv * 32 + rt * 16 + l16;
        af[rt] = *(const f16x8*)((const char*)As + r * 128 +
                                 ((ks * 64 + cbq) ^ ((r & 7) << 4)));
      }
#pragma unroll
      for (int ct = 0; ct < 8; ++ct) {
        const int r = ct * 16 + l16;
        bfr[ct] = *(const f16x8*)((const char*)Bs + r * 128 +
                                  ((ks * 64 + cbq) ^ ((r & 7) << 4)));
      }
#pragma unroll
      for (int rt = 0; rt < 2; ++rt)
#pragma unroll
        for (int ct = 0; ct < 8; ++ct)
          acc[rt][ct] = MFMA32(af[rt], bfr[ct], acc[rt][ct]);
    }
  }

#pragma unroll
  for (int ct = 0; ct < 8; ++ct) {
    const int g = by * 2 + (ct >> 2);
    const int h = g / 3, kk = g - h * 3;
    const int dd = (ct & 3) * 16 + l16;
#pragma unroll
    for (int rt = 0; rt < 2; ++rt) {
#pragma unroll
      for (int r = 0; r < 4; ++r) {
        int m = m0 + wv * 32 + rt * 16 + quad * 4 + r;
        int b = m >> 10, n = m & 1023;
        _Float16 val = (_Float16)acc[rt][ct][r];
        if (kk == 0)
          Qf[(((size_t)h * 16 + b) * 1024 + n) * 64 + dd] = val;
        else if (kk == 1)
          Kf[(((size_t)h * 16 + b) * 1024 + n) * 64 + dd] = val;
        else
          Vt[(((size_t)h * 16 + b) * 64 + dd) * 1024 + n] = val;
      }
    }
  }
}

// ---------------------------------------------------------------------------
// Kernel 2: flash attention per (h,b).  Block = 128 q rows (4 waves x 32),
// 16 KV tiles of 64, K/V staged in LDS with register prefetch.
// Trick: compute S^T = K.Q^T (operands swapped).  S^T's C/D layout
// (col=l16->q, row=quad*4+r->kv) IS the A-operand layout of the 16x16x16
// MFMA (m=l16, k=quad*4+j), so after exp2 the P fragments feed PV directly
// from registers.
// NEW: 1D grid + XCD-chunked swizzle so all 8 q-blocks of an (h,b) run on
// the SAME XCD (K/V fetched once per XCD L2 instead of 8x across XCDs).
// NEW: nontemporal Of stores (probe the 288MB->25MB WRITE_SIZE anomaly).
// ---------------------------------------------------------------------------
__global__ __launch_bounds__(256) void attn_kernel(
    const _Float16* __restrict__ Qf, const _Float16* __restrict__ Kf,
    const _Float16* __restrict__ Vt, _Float16* __restrict__ Of) {
  __shared__ _Float16 Ks[64][72];
  __shared__ _Float16 Vs[64][72];

  const int tid = threadIdx.x;
  const int wv = tid >> 6, lane = tid & 63, quad = lane >> 4, l16 = lane & 15;

  // 1536 blocks = 8 XCD * 192; chunk is hb-major so an hb's 8 q-blocks
  // stay on one XCD (its K/V = 256KB fits the 4MB XCD L2).
  const int flat = blockIdx.x;
  const int swz = (flat & 7) * 192 + (flat >> 3);
  const int hb = swz >> 3;
  const int h = hb >> 4, b = hb & 15;
  const _Float16* Q = Qf + (size_t)hb * 65536;
  const _Float16* K = Kf + (size_t)hb * 65536;
  const _Float16* V = Vt + (size_t)hb * 65536;  // [64 dd][1024 n]
  const int q0 = (swz & 7) * 128 + wv * 32;

  // Q fragments (B-operand: n=q=l16, k=d=quad*8+j), scale log2(e)/8 folded in
  const _Float16 cs = (_Float16)0.18033688011112042f;
  f16x8 qfr[2][2];
#pragma unroll
  for (int mi = 0; mi < 2; ++mi) {
    const _Float16* qp = Q + (size_t)(q0 + mi * 16 + l16) * 64 + quad * 8;
    qfr[mi][0] = *(const f16x8*)qp * cs;
    qfr[mi][1] = *(const f16x8*)(qp + 32) * cs;
  }

  // staging: thread covers rows r0 and r0+32, 8 cols from c0
  const int r0 = tid >> 3, c0 = (tid & 7) << 3;
  const _Float16* Kst = K + (size_t)r0 * 64 + c0;
  const _Float16* Vst = V + (size_t)r0 * 1024 + c0;

  uint4 kreg[2], vreg[2];
#pragma unroll
  for (int i = 0; i < 2; ++i) {
    kreg[i] = *(const uint4*)(Kst + i * 2048);
    vreg[i] = *(const uint4*)(Vst + i * 32768);
  }

  f32x4 o[2][4] = {};     // O^C: col(l16)=dd within dt, row(quad*4+r)=q
  float lsum[2] = {};     // per-lane row sums, q = l16

  for (int t = 0; t < 16; ++t) {
#pragma unroll
    for (int i = 0; i < 2; ++i) {
      *(uint4*)&Ks[r0 + i * 32][c0] = kreg[i];
      *(uint4*)&Vs[r0 + i * 32][c0] = vreg[i];
    }
    __syncthreads();
    if (t < 15) {
      int n1 = (t + 1) * 64;
#pragma unroll
      for (int i = 0; i < 2; ++i) {
        kreg[i] = *(const uint4*)(Kst + (size_t)n1 * 64 + i * 2048);
        vreg[i] = *(const uint4*)(Vst + n1 + i * 32768);
      }
    }

    // S^T = K.Q^T : A = K-frag (m=kv), B = Q-frag (n=q)
    f32x4 st[2][4] = {};
#pragma unroll
    for (int ct = 0; ct < 4; ++ct) {
      f16x8 k0 = *(const f16x8*)&Ks[ct * 16 + l16][quad * 8];
      f16x8 k1 = *(const f16x8*)&Ks[ct * 16 + l16][32 + quad * 8];
#pragma unroll
      for (int mi = 0; mi < 2; ++mi) {
        st[mi][ct] = MFMA32(k0, qfr[mi][0], st[mi][ct]);
        st[mi][ct] = MFMA32(k1, qfr[mi][1], st[mi][ct]);
      }
    }

    // P = exp2(S^T); lane-resident row sums; pack to 16x16x16 A-frags
    f16x4 pa[2][4];
#pragma unroll
    for (int mi = 0; mi < 2; ++mi)
#pragma unroll
      for (int ct = 0; ct < 4; ++ct)
#pragma unroll
        for (int r = 0; r < 4; ++r) {
          float p = __builtin_amdgcn_exp2f(st[mi][ct][r]);
          lsum[mi] += p;
          pa[mi][ct][r] = (_Float16)p;
        }

    // O += P.V  (x16 MFMA: A=pa (k=kv=ct*16+quad*4+r), B=V-frag b64 reads)
#pragma unroll
    for (int dt = 0; dt < 4; ++dt) {
#pragma unroll
      for (int kb = 0; kb < 4; ++kb) {
        f16x4 vf = *(const f16x4*)&Vs[dt * 16 + l16][kb * 16 + quad * 4];
#pragma unroll
        for (int mi = 0; mi < 2; ++mi)
          o[mi][dt] = MFMA16(pa[mi][kb], vf, o[mi][dt]);
      }
    }
    __syncthreads();
  }

  // reduce row sums across quads (each lane holds q=l16 partials)
#pragma unroll
  for (int mi = 0; mi < 2; ++mi) {
    float s = lsum[mi];
    s += __shfl_xor(s, 16, 64);
    s += __shfl_xor(s, 32, 64);
    lsum[mi] = s;  // all quads now hold full sum for q=l16
  }

  // Epilogue: O / l, store [b][n][h*64+dd] f16 (nontemporal)
#pragma unroll
  for (int mi = 0; mi < 2; ++mi) {
#pragma unroll
    for (int r = 0; r < 4; ++r) {
      float inv = 1.f / __shfl(lsum[mi], quad * 4 + r, 64);
      int n = q0 + mi * 16 + quad * 4 + r;
#pragma unroll
      for (int dt = 0; dt < 4; ++dt) {
        int dd = dt * 16 + l16;
        __builtin_nontemporal_store(
            (_Float16)(o[mi][dt][r] * inv),
            &Of[((size_t)b * 1024 + n) * 768 + h * 64 + dd]);
      }
    }
  }
}

// ---------------------------------------------------------------------------
// Kernel 3: output projection.  C[m][n] = sum_k Of[m][k] * U_msa[k][n].
// Same global_load_lds + XOR-swizzle staging as kernel 1.  f32 nt-store out.
// XCD-chunked swizzle: 768 = 8 * 96.
// ---------------------------------------------------------------------------
__global__ __launch_bounds__(256) void out_gemm_kernel(
    const _Float16* __restrict__ A, const _Float16* __restrict__ Bt,
    float* __restrict__ Cout) {
  __shared__ _Float16 As[128 * 64];
  __shared__ _Float16 Bs[128 * 64];

  const int tid = threadIdx.x;
  const int wv = tid >> 6, lane = tid & 63, quad = lane >> 4, l16 = lane & 15;

  const int flat = blockIdx.y * 128 + blockIdx.x;
  const int swz = (flat & 7) * 96 + (flat >> 3);
  const int m0 = (swz & 127) * 128;
  const int n0 = (swz >> 7) * 128;

  const int srow = lane >> 3;
  const int scol = ((lane & 7) ^ srow) << 3;
  const _Float16* Ag = A + (size_t)(m0 + srow) * 768 + scol;
  const _Float16* Bg = Bt + (size_t)(n0 + srow) * 768 + scol;

  const int cbq = quad * 16;

  f32x4 acc[2][8] = {};

  for (int k0 = 0; k0 < 768; k0 += 64) {
    __syncthreads();
#pragma unroll
    for (int i = 0; i < 4; ++i) {
      const int rb = (i * 4 + wv) * 8;
      GLOAD_LDS16(Ag + (size_t)rb * 768 + k0, (char*)As + rb * 128);
      GLOAD_LDS16(Bg + (size_t)rb * 768 + k0, (char*)Bs + rb * 128);
    }
    __syncthreads();
#pragma unroll
    for (int ks = 0; ks < 2; ++ks) {
      f16x8 af[2], bfr[8];
#pragma unroll
      for (int rt = 0; rt < 2; ++rt) {
        const int r = wv * 32 + rt * 16 + l16;
        af[rt] = *(const f16x8*)((const char*)As + r * 128 +
                                 ((ks * 64 + cbq) ^ ((r & 7) << 4)));
      }
#pragma unroll
      for (int ct = 0; ct < 8; ++ct) {
        const int r = ct * 16 + l16;
        bfr[ct] = *(const f16x8*)((const char*)Bs + r * 128 +
                                  ((ks * 64 + cbq) ^ ((r & 7) << 4)));
      }
#pragma unroll
      for (int rt = 0; rt < 2; ++rt)
#pragma unroll
        for (int ct = 0; ct < 8; ++ct)
          acc[rt][ct] = MFMA32(af[rt], bfr[ct], acc[rt][ct]);
    }
  }

#pragma unroll
  for (int rt = 0; rt < 2; ++rt) {
#pragma unroll
    for (int ct = 0; ct < 8; ++ct) {
#pragma unroll
      for (int r = 0; r < 4; ++r) {
        int m = m0 + wv * 32 + rt * 16 + quad * 4 + r;
        int n = n0 + ct * 16 + l16;
        __builtin_nontemporal_store(acc[rt][ct][r],
                                    &Cout[(size_t)m * 768 + n]);
      }
    }
  }
}

// ---------------------------------------------------------------------------
// Workspace layout (bytes), total 105,381,888:
//   Ut_qkv @ 0           36*64*768*2    =  3,538,944   ([2304][768] f16)
//   Ut_msa @ 3,538,944   768*768*2      =  1,179,648
//   zh/Of  @ 4,718,592   16384*768*2    = 25,165,824   (aliased)
//   Qf     @ 29,884,416  25,165,824
//   Kf     @ 55,050,240  25,165,824
//   Vt     @ 80,216,064  25,165,824  ([h][b][d][n])
// ---------------------------------------------------------------------------
extern "C" void kernel_launch(void* const* d_in, const int* in_sizes, int n_in,
                              void* d_out, int out_size, void* d_ws,
                              size_t ws_size, hipStream_t stream) {
  const float* z = (const float*)d_in[0];
  const float* Uqkv = (const float*)d_in[1];
  const float* Umsa = (const float*)d_in[2];

  char* ws = (char*)d_ws;
  _Float16* Ut_qkv = (_Float16*)(ws);
  _Float16* Ut_msa = (_Float16*)(ws + 3538944);
  _Float16* zh = (_Float16*)(ws + 4718592);
  _Float16* Of = zh;  // aliased (zh dead before attn writes Of)
  _Float16* Qf = (_Float16*)(ws + 29884416);
  _Float16* Kf = (_Float16*)(ws + 55050240);
  _Float16* Vt = (_Float16*)(ws + 80216064);

  tconv_kernel<<<dim3(192, 36), 256, 0, stream>>>(Uqkv, Ut_qkv, 768, 64);
  tconv_kernel<<<dim3(2304, 1), 256, 0, stream>>>(Umsa, Ut_msa, 768, 768);
  cvt16_kernel<<<dim3(6144, 1), 256, 0, stream>>>(z, zh, 16384 * 768);

  qkv_gemm_kernel<<<dim3(128, 18), 256, 0, stream>>>(zh, Ut_qkv, Qf, Kf, Vt);
  attn_kernel<<<dim3(1536, 1), 256, 0, stream>>>(Qf, Kf, Vt, Of);
  out_gemm_kernel<<<dim3(128, 6), 256, 0, stream>>>(Of, Ut_msa,
                                                    (float*)d_out);
}

// Round 2
// 358.398 us; speedup vs baseline: 1.1192x; 1.1192x over previous
//
#include <hip/hip_runtime.h>
#include <hip/hip_bf16.h>

typedef _Float16 f16x8 __attribute__((ext_vector_type(8)));
typedef _Float16 f16x4 __attribute__((ext_vector_type(4)));
typedef float f32x4 __attribute__((ext_vector_type(4)));

#define MFMA32(a, b, c) __builtin_amdgcn_mfma_f32_16x16x32_f16(a, b, c, 0, 0, 0)
#define MFMA16(a, b, c) __builtin_amdgcn_mfma_f32_16x16x16f16(a, b, c, 0, 0, 0)

// async global->LDS, 16B per lane, linear dest (wave base + lane*16)
#define GLOAD_LDS16(g, l)                                         \
  __builtin_amdgcn_global_load_lds(                               \
      (const __attribute__((address_space(1))) void*)(g),         \
      (__attribute__((address_space(3))) void*)(l), 16, 0, 0)

// ---------------------------------------------------------------------------
// Kernel 0a: batched transpose + f32->f16 convert.
// ---------------------------------------------------------------------------
__global__ __launch_bounds__(256) void tconv_kernel(
    const float* __restrict__ in, _Float16* __restrict__ out, int R, int C) {
  size_t bat = (size_t)blockIdx.y * R * C;
  int o = blockIdx.x * 256 + threadIdx.x;
  if (o < R * C) {
    int c = o / R, r = o - c * R;
    out[bat + o] = (_Float16)in[bat + (size_t)r * C + c];
  }
}

// ---------------------------------------------------------------------------
// Kernel 0b: straight f32 -> f16 convert, 8 elts/thread.
// ---------------------------------------------------------------------------
__global__ __launch_bounds__(256) void cvt16_kernel(
    const float* __restrict__ in, _Float16* __restrict__ out, int n) {
  int i = (blockIdx.x * 256 + threadIdx.x) * 8;
  if (i < n) {
    float4 a = *(const float4*)(in + i);
    float4 b = *(const float4*)(in + i + 4);
    f16x8 cv;
    cv[0] = (_Float16)a.x; cv[1] = (_Float16)a.y;
    cv[2] = (_Float16)a.z; cv[3] = (_Float16)a.w;
    cv[4] = (_Float16)b.x; cv[5] = (_Float16)b.y;
    cv[6] = (_Float16)b.z; cv[7] = (_Float16)b.w;
    *(f16x8*)(out + i) = cv;
  }
}

// ---------------------------------------------------------------------------
// Kernel 1: fused QKV projection as ONE GEMM.
// C[m][n] = sum_e zh[m][e] * Ut[n][e],  M=16384, N=2304, K=768.
// global_load_lds staging into unpadded [128][64] f16 LDS with XOR swizzle
// (both-sides: pre-swizzled global source + swizzled ds_read).
// Grid mapping REVERTED to plain x-fastest: XCD = x%8 partitions M, so each
// XCD's A working set is 16 m-tiles = 3.1MB (L2-resident across the kernel).
// The R1 288-chunk swizzle gave every XCD the full 25MB A -> ~8x A re-fetch.
// ---------------------------------------------------------------------------
__global__ __launch_bounds__(256) void qkv_gemm_kernel(
    const _Float16* __restrict__ zh, const _Float16* __restrict__ Ut,
    _Float16* __restrict__ Qf, _Float16* __restrict__ Kf,
    _Float16* __restrict__ Vt) {
  __shared__ _Float16 As[128 * 64];
  __shared__ _Float16 Bs[128 * 64];

  const int tid = threadIdx.x;
  const int wv = tid >> 6, lane = tid & 63, quad = lane >> 4, l16 = lane & 15;

  const int m0 = blockIdx.x * 128;
  const int by = blockIdx.y;
  const int n0 = by * 128;

  const int srow = lane >> 3;
  const int scol = ((lane & 7) ^ srow) << 3;  // f16 units, inverse swizzle
  const _Float16* Ag = zh + (size_t)(m0 + srow) * 768 + scol;
  const _Float16* Bg = Ut + (size_t)(n0 + srow) * 768 + scol;

  const int cbq = quad * 16;  // byte col of this lane's fragment within row

  f32x4 acc[2][8] = {};

  for (int k0 = 0; k0 < 768; k0 += 64) {
    __syncthreads();
#pragma unroll
    for (int i = 0; i < 4; ++i) {
      const int rb = (i * 4 + wv) * 8;
      GLOAD_LDS16(Ag + (size_t)rb * 768 + k0, (char*)As + rb * 128);
      GLOAD_LDS16(Bg + (size_t)rb * 768 + k0, (char*)Bs + rb * 128);
    }
    __syncthreads();
#pragma unroll
    for (int ks = 0; ks < 2; ++ks) {
      f16x8 af[2], bfr[8];
#pragma unroll
      for (int rt = 0; rt < 2; ++rt) {
        const int r = wv * 32 + rt * 16 + l16;
        af[rt] = *(const f16x8*)((const char*)As + r * 128 +
                                 ((ks * 64 + cbq) ^ ((r & 7) << 4)));
      }
#pragma unroll
      for (int ct = 0; ct < 8; ++ct) {
        const int r = ct * 16 + l16;
        bfr[ct] = *(const f16x8*)((const char*)Bs + r * 128 +
                                  ((ks * 64 + cbq) ^ ((r & 7) << 4)));
      }
#pragma unroll
      for (int rt = 0; rt < 2; ++rt)
#pragma unroll
        for (int ct = 0; ct < 8; ++ct)
          acc[rt][ct] = MFMA32(af[rt], bfr[ct], acc[rt][ct]);
    }
  }

#pragma unroll
  for (int ct = 0; ct < 8; ++ct) {
    const int g = by * 2 + (ct >> 2);
    const int h = g / 3, kk = g - h * 3;
    const int dd = (ct & 3) * 16 + l16;
#pragma unroll
    for (int rt = 0; rt < 2; ++rt) {
#pragma unroll
      for (int r = 0; r < 4; ++r) {
        int m = m0 + wv * 32 + rt * 16 + quad * 4 + r;
        int b = m >> 10, n = m & 1023;
        _Float16 val = (_Float16)acc[rt][ct][r];
        if (kk == 0)
          Qf[(((size_t)h * 16 + b) * 1024 + n) * 64 + dd] = val;
        else if (kk == 1)
          Kf[(((size_t)h * 16 + b) * 1024 + n) * 64 + dd] = val;
        else
          Vt[(((size_t)h * 16 + b) * 64 + dd) * 1024 + n] = val;
      }
    }
  }
}

// ---------------------------------------------------------------------------
// Kernel 2: flash attention per (h,b).  Block = 128 q rows (4 waves x 32),
// 16 KV tiles of 64.
// NEW vs R1: double-buffered K/V LDS -> ONE barrier per tile (was two), so
// the write of tile t+1 overlaps compute of tile t and waves decouple.
// s_setprio(1) around both MFMA clusters (measured +4-7% on attn-like
// phase-split schedules).  XCD-chunked 1D grid kept (FETCH 130->43MB in R1).
// nt-stores for Of kept (WRITE 280->93MB in R1).
// ---------------------------------------------------------------------------
__global__ __launch_bounds__(256) void attn_kernel(
    const _Float16* __restrict__ Qf, const _Float16* __restrict__ Kf,
    const _Float16* __restrict__ Vt, _Float16* __restrict__ Of) {
  __shared__ _Float16 Ks[2][64][72];
  __shared__ _Float16 Vs[2][64][72];

  const int tid = threadIdx.x;
  const int wv = tid >> 6, lane = tid & 63, quad = lane >> 4, l16 = lane & 15;

  // 1536 blocks = 8 XCD * 192; chunk is hb-major so an hb's 8 q-blocks
  // stay on one XCD (K/V = 256KB resident in the 4MB XCD L2).
  const int flat = blockIdx.x;
  const int swz = (flat & 7) * 192 + (flat >> 3);
  const int hb = swz >> 3;
  const int h = hb >> 4, b = hb & 15;
  const _Float16* Q = Qf + (size_t)hb * 65536;
  const _Float16* K = Kf + (size_t)hb * 65536;
  const _Float16* V = Vt + (size_t)hb * 65536;  // [64 dd][1024 n]
  const int q0 = (swz & 7) * 128 + wv * 32;

  // Q fragments (B-operand: n=q=l16, k=d=quad*8+j), scale log2(e)/8 folded in
  const _Float16 cs = (_Float16)0.18033688011112042f;
  f16x8 qfr[2][2];
#pragma unroll
  for (int mi = 0; mi < 2; ++mi) {
    const _Float16* qp = Q + (size_t)(q0 + mi * 16 + l16) * 64 + quad * 8;
    qfr[mi][0] = *(const f16x8*)qp * cs;
    qfr[mi][1] = *(const f16x8*)(qp + 32) * cs;
  }

  // staging: thread covers rows r0 and r0+32, 8 cols from c0
  const int r0 = tid >> 3, c0 = (tid & 7) << 3;
  const _Float16* Kst = K + (size_t)r0 * 64 + c0;
  const _Float16* Vst = V + (size_t)r0 * 1024 + c0;

  uint4 kreg[2], vreg[2];
#pragma unroll
  for (int i = 0; i < 2; ++i) {
    kreg[i] = *(const uint4*)(Kst + i * 2048);
    vreg[i] = *(const uint4*)(Vst + i * 32768);
  }
#pragma unroll
  for (int i = 0; i < 2; ++i) {
    *(uint4*)&Ks[0][r0 + i * 32][c0] = kreg[i];
    *(uint4*)&Vs[0][r0 + i * 32][c0] = vreg[i];
  }
  __syncthreads();

  f32x4 o[2][4] = {};     // O^C: col(l16)=dd within dt, row(quad*4+r)=q
  float lsum[2] = {};     // per-lane row sums, q = l16

  for (int t = 0; t < 16; ++t) {
    const int cur = t & 1;
    // prefetch t+1 into regs (latency hidden under this tile's compute)
    if (t < 15) {
      int n1 = (t + 1) * 64;
#pragma unroll
      for (int i = 0; i < 2; ++i) {
        kreg[i] = *(const uint4*)(Kst + (size_t)n1 * 64 + i * 2048);
        vreg[i] = *(const uint4*)(Vst + n1 + i * 32768);
      }
    }

    // S^T = K.Q^T : A = K-frag (m=kv), B = Q-frag (n=q)
    f32x4 st[2][4] = {};
    __builtin_amdgcn_s_setprio(1);
#pragma unroll
    for (int ct = 0; ct < 4; ++ct) {
      f16x8 kf0 = *(const f16x8*)&Ks[cur][ct * 16 + l16][quad * 8];
      f16x8 kf1 = *(const f16x8*)&Ks[cur][ct * 16 + l16][32 + quad * 8];
#pragma unroll
      for (int mi = 0; mi < 2; ++mi) {
        st[mi][ct] = MFMA32(kf0, qfr[mi][0], st[mi][ct]);
        st[mi][ct] = MFMA32(kf1, qfr[mi][1], st[mi][ct]);
      }
    }
    __builtin_amdgcn_s_setprio(0);

    // P = exp2(S^T); lane-resident row sums; pack to 16x16x16 A-frags
    f16x4 pa[2][4];
#pragma unroll
    for (int mi = 0; mi < 2; ++mi)
#pragma unroll
      for (int ct = 0; ct < 4; ++ct)
#pragma unroll
        for (int r = 0; r < 4; ++r) {
          float p = __builtin_amdgcn_exp2f(st[mi][ct][r]);
          lsum[mi] += p;
          pa[mi][ct][r] = (_Float16)p;
        }

    // O += P.V  (x16 MFMA: A=pa (k=kv), B=V-frag b64 reads)
    __builtin_amdgcn_s_setprio(1);
#pragma unroll
    for (int dt = 0; dt < 4; ++dt) {
#pragma unroll
      for (int kb = 0; kb < 4; ++kb) {
        f16x4 vf = *(const f16x4*)&Vs[cur][dt * 16 + l16][kb * 16 + quad * 4];
#pragma unroll
        for (int mi = 0; mi < 2; ++mi)
          o[mi][dt] = MFMA16(pa[mi][kb], vf, o[mi][dt]);
      }
    }
    __builtin_amdgcn_s_setprio(0);

    // write t+1 into the other buffer (released to readers by ONE barrier)
    if (t < 15) {
#pragma unroll
      for (int i = 0; i < 2; ++i) {
        *(uint4*)&Ks[cur ^ 1][r0 + i * 32][c0] = kreg[i];
        *(uint4*)&Vs[cur ^ 1][r0 + i * 32][c0] = vreg[i];
      }
      __syncthreads();
    }
  }

  // reduce row sums across quads (each lane holds q=l16 partials)
#pragma unroll
  for (int mi = 0; mi < 2; ++mi) {
    float s = lsum[mi];
    s += __shfl_xor(s, 16, 64);
    s += __shfl_xor(s, 32, 64);
    lsum[mi] = s;
  }

  // Epilogue: O / l, store [b][n][h*64+dd] f16 (nontemporal)
#pragma unroll
  for (int mi = 0; mi < 2; ++mi) {
#pragma unroll
    for (int r = 0; r < 4; ++r) {
      float inv = 1.f / __shfl(lsum[mi], quad * 4 + r, 64);
      int n = q0 + mi * 16 + quad * 4 + r;
#pragma unroll
      for (int dt = 0; dt < 4; ++dt) {
        int dd = dt * 16 + l16;
        __builtin_nontemporal_store(
            (_Float16)(o[mi][dt][r] * inv),
            &Of[((size_t)b * 1024 + n) * 768 + h * 64 + dd]);
      }
    }
  }
}

// ---------------------------------------------------------------------------
// Kernel 3: output projection.  C[m][n] = sum_k Of[m][k] * U_msa[k][n].
// global_load_lds + XOR-swizzle staging; grid swizzle REVERTED (XCD = x%8
// partitions M; B is 1.2MB, trivially resident everywhere).
// ---------------------------------------------------------------------------
__global__ __launch_bounds__(256) void out_gemm_kernel(
    const _Float16* __restrict__ A, const _Float16* __restrict__ Bt,
    float* __restrict__ Cout) {
  __shared__ _Float16 As[128 * 64];
  __shared__ _Float16 Bs[128 * 64];

  const int tid = threadIdx.x;
  const int wv = tid >> 6, lane = tid & 63, quad = lane >> 4, l16 = lane & 15;

  const int m0 = blockIdx.x * 128;
  const int n0 = blockIdx.y * 128;

  const int srow = lane >> 3;
  const int scol = ((lane & 7) ^ srow) << 3;
  const _Float16* Ag = A + (size_t)(m0 + srow) * 768 + scol;
  const _Float16* Bg = Bt + (size_t)(n0 + srow) * 768 + scol;

  const int cbq = quad * 16;

  f32x4 acc[2][8] = {};

  for (int k0 = 0; k0 < 768; k0 += 64) {
    __syncthreads();
#pragma unroll
    for (int i = 0; i < 4; ++i) {
      const int rb = (i * 4 + wv) * 8;
      GLOAD_LDS16(Ag + (size_t)rb * 768 + k0, (char*)As + rb * 128);
      GLOAD_LDS16(Bg + (size_t)rb * 768 + k0, (char*)Bs + rb * 128);
    }
    __syncthreads();
#pragma unroll
    for (int ks = 0; ks < 2; ++ks) {
      f16x8 af[2], bfr[8];
#pragma unroll
      for (int rt = 0; rt < 2; ++rt) {
        const int r = wv * 32 + rt * 16 + l16;
        af[rt] = *(const f16x8*)((const char*)As + r * 128 +
                                 ((ks * 64 + cbq) ^ ((r & 7) << 4)));
      }
#pragma unroll
      for (int ct = 0; ct < 8; ++ct) {
        const int r = ct * 16 + l16;
        bfr[ct] = *(const f16x8*)((const char*)Bs + r * 128 +
                                  ((ks * 64 + cbq) ^ ((r & 7) << 4)));
      }
#pragma unroll
      for (int rt = 0; rt < 2; ++rt)
#pragma unroll
        for (int ct = 0; ct < 8; ++ct)
          acc[rt][ct] = MFMA32(af[rt], bfr[ct], acc[rt][ct]);
    }
  }

#pragma unroll
  for (int rt = 0; rt < 2; ++rt) {
#pragma unroll
    for (int ct = 0; ct < 8; ++ct) {
#pragma unroll
      for (int r = 0; r < 4; ++r) {
        int m = m0 + wv * 32 + rt * 16 + quad * 4 + r;
        int n = n0 + ct * 16 + l16;
        __builtin_nontemporal_store(acc[rt][ct][r],
                                    &Cout[(size_t)m * 768 + n]);
      }
    }
  }
}

// ---------------------------------------------------------------------------
// Workspace layout (bytes), total 105,381,888:
//   Ut_qkv @ 0           36*64*768*2    =  3,538,944   ([2304][768] f16)
//   Ut_msa @ 3,538,944   768*768*2      =  1,179,648
//   zh/Of  @ 4,718,592   16384*768*2    = 25,165,824   (aliased)
//   Qf     @ 29,884,416  25,165,824
//   Kf     @ 55,050,240  25,165,824
//   Vt     @ 80,216,064  25,165,824  ([h][b][d][n])
// ---------------------------------------------------------------------------
extern "C" void kernel_launch(void* const* d_in, const int* in_sizes, int n_in,
                              void* d_out, int out_size, void* d_ws,
                              size_t ws_size, hipStream_t stream) {
  const float* z = (const float*)d_in[0];
  const float* Uqkv = (const float*)d_in[1];
  const float* Umsa = (const float*)d_in[2];

  char* ws = (char*)d_ws;
  _Float16* Ut_qkv = (_Float16*)(ws);
  _Float16* Ut_msa = (_Float16*)(ws + 3538944);
  _Float16* zh = (_Float16*)(ws + 4718592);
  _Float16* Of = zh;  // aliased (zh dead before attn writes Of)
  _Float16* Qf = (_Float16*)(ws + 29884416);
  _Float16* Kf = (_Float16*)(ws + 55050240);
  _Float16* Vt = (_Float16*)(ws + 80216064);

  tconv_kernel<<<dim3(192, 36), 256, 0, stream>>>(Uqkv, Ut_qkv, 768, 64);
  tconv_kernel<<<dim3(2304, 1), 256, 0, stream>>>(Umsa, Ut_msa, 768, 768);
  cvt16_kernel<<<dim3(6144, 1), 256, 0, stream>>>(z, zh, 16384 * 768);

  qkv_gemm_kernel<<<dim3(128, 18), 256, 0, stream>>>(zh, Ut_qkv, Qf, Kf, Vt);
  attn_kernel<<<dim3(1536, 1), 256, 0, stream>>>(Qf, Kf, Vt, Of);
  out_gemm_kernel<<<dim3(128, 6), 256, 0, stream>>>(Of, Ut_msa,
                                                    (float*)d_out);
}

// Round 3
// 347.638 us; speedup vs baseline: 1.1539x; 1.0310x over previous
//
#include <hip/hip_runtime.h>
#include <hip/hip_bf16.h>

typedef _Float16 f16x8 __attribute__((ext_vector_type(8)));
typedef _Float16 f16x4 __attribute__((ext_vector_type(4)));
typedef float f32x4 __attribute__((ext_vector_type(4)));

#define MFMA32(a, b, c) __builtin_amdgcn_mfma_f32_16x16x32_f16(a, b, c, 0, 0, 0)
#define MFMA16(a, b, c) __builtin_amdgcn_mfma_f32_16x16x16f16(a, b, c, 0, 0, 0)

// async global->LDS, 16B per lane, linear dest (wave base + lane*16)
#define GLOAD_LDS16(g, l)                                         \
  __builtin_amdgcn_global_load_lds(                               \
      (const __attribute__((address_space(1))) void*)(g),         \
      (__attribute__((address_space(3))) void*)(l), 16, 0, 0)

// ---------------------------------------------------------------------------
// Kernel 0a: batched transpose + f32->f16 convert.
// ---------------------------------------------------------------------------
__global__ __launch_bounds__(256) void tconv_kernel(
    const float* __restrict__ in, _Float16* __restrict__ out, int R, int C) {
  size_t bat = (size_t)blockIdx.y * R * C;
  int o = blockIdx.x * 256 + threadIdx.x;
  if (o < R * C) {
    int c = o / R, r = o - c * R;
    out[bat + o] = (_Float16)in[bat + (size_t)r * C + c];
  }
}

// ---------------------------------------------------------------------------
// Kernel 0b: straight f32 -> f16 convert, 8 elts/thread.
// ---------------------------------------------------------------------------
__global__ __launch_bounds__(256) void cvt16_kernel(
    const float* __restrict__ in, _Float16* __restrict__ out, int n) {
  int i = (blockIdx.x * 256 + threadIdx.x) * 8;
  if (i < n) {
    float4 a = *(const float4*)(in + i);
    float4 b = *(const float4*)(in + i + 4);
    f16x8 cv;
    cv[0] = (_Float16)a.x; cv[1] = (_Float16)a.y;
    cv[2] = (_Float16)a.z; cv[3] = (_Float16)a.w;
    cv[4] = (_Float16)b.x; cv[5] = (_Float16)b.y;
    cv[6] = (_Float16)b.z; cv[7] = (_Float16)b.w;
    *(f16x8*)(out + i) = cv;
  }
}

// ---------------------------------------------------------------------------
// Kernel 1: fused QKV projection as ONE GEMM.
// C[m][n] = sum_e zh[m][e] * Ut[n][e],  M=16384, N=2304, K=768.
// NEW (R3): counted-wait double-buffered pipeline ("minimum 2-phase"):
//   - LDS 2x(A16K+B16K)=64KB, global_load_lds stages tile t+1 at the TOP of
//     iteration t (async, stays in flight under the MFMA cluster),
//   - raw s_barrier (no implicit vmcnt(0)/lgkmcnt(0) drain of __syncthreads),
//   - ONE barrier per K-step, preceded by vmcnt(0) that is nearly free
//     because the loads had the whole MFMA phase to land.
// WAR safety: reads of buf[cur^1] complete before the t-1 barrier (each
// ds_read is consumed by an MFMA issued before the barrier), so staging into
// it after that barrier is race-free.
// XOR-swizzle staging kept (bank conflicts measured 0).
// ---------------------------------------------------------------------------
__global__ __launch_bounds__(256) void qkv_gemm_kernel(
    const _Float16* __restrict__ zh, const _Float16* __restrict__ Ut,
    _Float16* __restrict__ Qf, _Float16* __restrict__ Kf,
    _Float16* __restrict__ Vt) {
  __shared__ _Float16 As[2][128 * 64];
  __shared__ _Float16 Bs[2][128 * 64];

  const int tid = threadIdx.x;
  const int wv = tid >> 6, lane = tid & 63, quad = lane >> 4, l16 = lane & 15;

  const int m0 = blockIdx.x * 128;
  const int by = blockIdx.y;
  const int n0 = by * 128;

  const int srow = lane >> 3;
  const int scol = ((lane & 7) ^ srow) << 3;  // f16 units, inverse swizzle
  const _Float16* Ag = zh + (size_t)(m0 + srow) * 768 + scol;
  const _Float16* Bg = Ut + (size_t)(n0 + srow) * 768 + scol;

  const int cbq = quad * 16;  // byte col of this lane's fragment within row

  f32x4 acc[2][8] = {};

  // prologue: stage K-tile 0 into buffer 0
#pragma unroll
  for (int i = 0; i < 4; ++i) {
    const int rb = (i * 4 + wv) * 8;
    GLOAD_LDS16(Ag + (size_t)rb * 768, (char*)As[0] + rb * 128);
    GLOAD_LDS16(Bg + (size_t)rb * 768, (char*)Bs[0] + rb * 128);
  }
  asm volatile("s_waitcnt vmcnt(0)" ::: "memory");
  __builtin_amdgcn_s_barrier();

  for (int t = 0; t < 12; ++t) {
    const int cur = t & 1;
    // issue next tile's loads (async; in flight under this tile's MFMAs)
    if (t < 11) {
      const int k1 = (t + 1) * 64;
#pragma unroll
      for (int i = 0; i < 4; ++i) {
        const int rb = (i * 4 + wv) * 8;
        GLOAD_LDS16(Ag + (size_t)rb * 768 + k1,
                    (char*)As[cur ^ 1] + rb * 128);
        GLOAD_LDS16(Bg + (size_t)rb * 768 + k1,
                    (char*)Bs[cur ^ 1] + rb * 128);
      }
    }
#pragma unroll
    for (int ks = 0; ks < 2; ++ks) {
      f16x8 af[2], bfr[8];
#pragma unroll
      for (int rt = 0; rt < 2; ++rt) {
        const int r = wv * 32 + rt * 16 + l16;
        af[rt] = *(const f16x8*)((const char*)As[cur] + r * 128 +
                                 ((ks * 64 + cbq) ^ ((r & 7) << 4)));
      }
#pragma unroll
      for (int ct = 0; ct < 8; ++ct) {
        const int r = ct * 16 + l16;
        bfr[ct] = *(const f16x8*)((const char*)Bs[cur] + r * 128 +
                                  ((ks * 64 + cbq) ^ ((r & 7) << 4)));
      }
#pragma unroll
      for (int rt = 0; rt < 2; ++rt)
#pragma unroll
        for (int ct = 0; ct < 8; ++ct)
          acc[rt][ct] = MFMA32(af[rt], bfr[ct], acc[rt][ct]);
    }
    if (t < 11) {
      asm volatile("s_waitcnt vmcnt(0)" ::: "memory");
      __builtin_amdgcn_s_barrier();
    }
  }

#pragma unroll
  for (int ct = 0; ct < 8; ++ct) {
    const int g = by * 2 + (ct >> 2);
    const int h = g / 3, kk = g - h * 3;
    const int dd = (ct & 3) * 16 + l16;
#pragma unroll
    for (int rt = 0; rt < 2; ++rt) {
#pragma unroll
      for (int r = 0; r < 4; ++r) {
        int m = m0 + wv * 32 + rt * 16 + quad * 4 + r;
        int b = m >> 10, n = m & 1023;
        _Float16 val = (_Float16)acc[rt][ct][r];
        if (kk == 0)
          Qf[(((size_t)h * 16 + b) * 1024 + n) * 64 + dd] = val;
        else if (kk == 1)
          Kf[(((size_t)h * 16 + b) * 1024 + n) * 64 + dd] = val;
        else
          Vt[(((size_t)h * 16 + b) * 64 + dd) * 1024 + n] = val;
      }
    }
  }
}

// ---------------------------------------------------------------------------
// Kernel 2: flash attention per (h,b).  (unchanged from R2 — it left the
// top-5: dbuf K/V LDS, one barrier/tile, setprio on MFMA clusters,
// XCD-chunked grid, nt-stores.)
// ---------------------------------------------------------------------------
__global__ __launch_bounds__(256) void attn_kernel(
    const _Float16* __restrict__ Qf, const _Float16* __restrict__ Kf,
    const _Float16* __restrict__ Vt, _Float16* __restrict__ Of) {
  __shared__ _Float16 Ks[2][64][72];
  __shared__ _Float16 Vs[2][64][72];

  const int tid = threadIdx.x;
  const int wv = tid >> 6, lane = tid & 63, quad = lane >> 4, l16 = lane & 15;

  const int flat = blockIdx.x;
  const int swz = (flat & 7) * 192 + (flat >> 3);
  const int hb = swz >> 3;
  const int h = hb >> 4, b = hb & 15;
  const _Float16* Q = Qf + (size_t)hb * 65536;
  const _Float16* K = Kf + (size_t)hb * 65536;
  const _Float16* V = Vt + (size_t)hb * 65536;  // [64 dd][1024 n]
  const int q0 = (swz & 7) * 128 + wv * 32;

  const _Float16 cs = (_Float16)0.18033688011112042f;
  f16x8 qfr[2][2];
#pragma unroll
  for (int mi = 0; mi < 2; ++mi) {
    const _Float16* qp = Q + (size_t)(q0 + mi * 16 + l16) * 64 + quad * 8;
    qfr[mi][0] = *(const f16x8*)qp * cs;
    qfr[mi][1] = *(const f16x8*)(qp + 32) * cs;
  }

  const int r0 = tid >> 3, c0 = (tid & 7) << 3;
  const _Float16* Kst = K + (size_t)r0 * 64 + c0;
  const _Float16* Vst = V + (size_t)r0 * 1024 + c0;

  uint4 kreg[2], vreg[2];
#pragma unroll
  for (int i = 0; i < 2; ++i) {
    kreg[i] = *(const uint4*)(Kst + i * 2048);
    vreg[i] = *(const uint4*)(Vst + i * 32768);
  }
#pragma unroll
  for (int i = 0; i < 2; ++i) {
    *(uint4*)&Ks[0][r0 + i * 32][c0] = kreg[i];
    *(uint4*)&Vs[0][r0 + i * 32][c0] = vreg[i];
  }
  __syncthreads();

  f32x4 o[2][4] = {};
  float lsum[2] = {};

  for (int t = 0; t < 16; ++t) {
    const int cur = t & 1;
    if (t < 15) {
      int n1 = (t + 1) * 64;
#pragma unroll
      for (int i = 0; i < 2; ++i) {
        kreg[i] = *(const uint4*)(Kst + (size_t)n1 * 64 + i * 2048);
        vreg[i] = *(const uint4*)(Vst + n1 + i * 32768);
      }
    }

    f32x4 st[2][4] = {};
    __builtin_amdgcn_s_setprio(1);
#pragma unroll
    for (int ct = 0; ct < 4; ++ct) {
      f16x8 kf0 = *(const f16x8*)&Ks[cur][ct * 16 + l16][quad * 8];
      f16x8 kf1 = *(const f16x8*)&Ks[cur][ct * 16 + l16][32 + quad * 8];
#pragma unroll
      for (int mi = 0; mi < 2; ++mi) {
        st[mi][ct] = MFMA32(kf0, qfr[mi][0], st[mi][ct]);
        st[mi][ct] = MFMA32(kf1, qfr[mi][1], st[mi][ct]);
      }
    }
    __builtin_amdgcn_s_setprio(0);

    f16x4 pa[2][4];
#pragma unroll
    for (int mi = 0; mi < 2; ++mi)
#pragma unroll
      for (int ct = 0; ct < 4; ++ct)
#pragma unroll
        for (int r = 0; r < 4; ++r) {
          float p = __builtin_amdgcn_exp2f(st[mi][ct][r]);
          lsum[mi] += p;
          pa[mi][ct][r] = (_Float16)p;
        }

    __builtin_amdgcn_s_setprio(1);
#pragma unroll
    for (int dt = 0; dt < 4; ++dt) {
#pragma unroll
      for (int kb = 0; kb < 4; ++kb) {
        f16x4 vf = *(const f16x4*)&Vs[cur][dt * 16 + l16][kb * 16 + quad * 4];
#pragma unroll
        for (int mi = 0; mi < 2; ++mi)
          o[mi][dt] = MFMA16(pa[mi][kb], vf, o[mi][dt]);
      }
    }
    __builtin_amdgcn_s_setprio(0);

    if (t < 15) {
#pragma unroll
      for (int i = 0; i < 2; ++i) {
        *(uint4*)&Ks[cur ^ 1][r0 + i * 32][c0] = kreg[i];
        *(uint4*)&Vs[cur ^ 1][r0 + i * 32][c0] = vreg[i];
      }
      __syncthreads();
    }
  }

#pragma unroll
  for (int mi = 0; mi < 2; ++mi) {
    float s = lsum[mi];
    s += __shfl_xor(s, 16, 64);
    s += __shfl_xor(s, 32, 64);
    lsum[mi] = s;
  }

#pragma unroll
  for (int mi = 0; mi < 2; ++mi) {
#pragma unroll
    for (int r = 0; r < 4; ++r) {
      float inv = 1.f / __shfl(lsum[mi], quad * 4 + r, 64);
      int n = q0 + mi * 16 + quad * 4 + r;
#pragma unroll
      for (int dt = 0; dt < 4; ++dt) {
        int dd = dt * 16 + l16;
        __builtin_nontemporal_store(
            (_Float16)(o[mi][dt][r] * inv),
            &Of[((size_t)b * 1024 + n) * 768 + h * 64 + dd]);
      }
    }
  }
}

// ---------------------------------------------------------------------------
// Kernel 3: output projection.  C[m][n] = sum_k Of[m][k] * U_msa[k][n].
// Same counted-wait double-buffered pipeline as kernel 1.
// ---------------------------------------------------------------------------
__global__ __launch_bounds__(256) void out_gemm_kernel(
    const _Float16* __restrict__ A, const _Float16* __restrict__ Bt,
    float* __restrict__ Cout) {
  __shared__ _Float16 As[2][128 * 64];
  __shared__ _Float16 Bs[2][128 * 64];

  const int tid = threadIdx.x;
  const int wv = tid >> 6, lane = tid & 63, quad = lane >> 4, l16 = lane & 15;

  const int m0 = blockIdx.x * 128;
  const int n0 = blockIdx.y * 128;

  const int srow = lane >> 3;
  const int scol = ((lane & 7) ^ srow) << 3;
  const _Float16* Ag = A + (size_t)(m0 + srow) * 768 + scol;
  const _Float16* Bg = Bt + (size_t)(n0 + srow) * 768 + scol;

  const int cbq = quad * 16;

  f32x4 acc[2][8] = {};

#pragma unroll
  for (int i = 0; i < 4; ++i) {
    const int rb = (i * 4 + wv) * 8;
    GLOAD_LDS16(Ag + (size_t)rb * 768, (char*)As[0] + rb * 128);
    GLOAD_LDS16(Bg + (size_t)rb * 768, (char*)Bs[0] + rb * 128);
  }
  asm volatile("s_waitcnt vmcnt(0)" ::: "memory");
  __builtin_amdgcn_s_barrier();

  for (int t = 0; t < 12; ++t) {
    const int cur = t & 1;
    if (t < 11) {
      const int k1 = (t + 1) * 64;
#pragma unroll
      for (int i = 0; i < 4; ++i) {
        const int rb = (i * 4 + wv) * 8;
        GLOAD_LDS16(Ag + (size_t)rb * 768 + k1,
                    (char*)As[cur ^ 1] + rb * 128);
        GLOAD_LDS16(Bg + (size_t)rb * 768 + k1,
                    (char*)Bs[cur ^ 1] + rb * 128);
      }
    }
#pragma unroll
    for (int ks = 0; ks < 2; ++ks) {
      f16x8 af[2], bfr[8];
#pragma unroll
      for (int rt = 0; rt < 2; ++rt) {
        const int r = wv * 32 + rt * 16 + l16;
        af[rt] = *(const f16x8*)((const char*)As[cur] + r * 128 +
                                 ((ks * 64 + cbq) ^ ((r & 7) << 4)));
      }
#pragma unroll
      for (int ct = 0; ct < 8; ++ct) {
        const int r = ct * 16 + l16;
        bfr[ct] = *(const f16x8*)((const char*)Bs[cur] + r * 128 +
                                  ((ks * 64 + cbq) ^ ((r & 7) << 4)));
      }
#pragma unroll
      for (int rt = 0; rt < 2; ++rt)
#pragma unroll
        for (int ct = 0; ct < 8; ++ct)
          acc[rt][ct] = MFMA32(af[rt], bfr[ct], acc[rt][ct]);
    }
    if (t < 11) {
      asm volatile("s_waitcnt vmcnt(0)" ::: "memory");
      __builtin_amdgcn_s_barrier();
    }
  }

#pragma unroll
  for (int rt = 0; rt < 2; ++rt) {
#pragma unroll
    for (int ct = 0; ct < 8; ++ct) {
#pragma unroll
      for (int r = 0; r < 4; ++r) {
        int m = m0 + wv * 32 + rt * 16 + quad * 4 + r;
        int n = n0 + ct * 16 + l16;
        __builtin_nontemporal_store(acc[rt][ct][r],
                                    &Cout[(size_t)m * 768 + n]);
      }
    }
  }
}

// ---------------------------------------------------------------------------
// Workspace layout (bytes), total 105,381,888:
//   Ut_qkv @ 0           36*64*768*2    =  3,538,944   ([2304][768] f16)
//   Ut_msa @ 3,538,944   768*768*2      =  1,179,648
//   zh/Of  @ 4,718,592   16384*768*2    = 25,165,824   (aliased)
//   Qf     @ 29,884,416  25,165,824
//   Kf     @ 55,050,240  25,165,824
//   Vt     @ 80,216,064  25,165,824  ([h][b][d][n])
// ---------------------------------------------------------------------------
extern "C" void kernel_launch(void* const* d_in, const int* in_sizes, int n_in,
                              void* d_out, int out_size, void* d_ws,
                              size_t ws_size, hipStream_t stream) {
  const float* z = (const float*)d_in[0];
  const float* Uqkv = (const float*)d_in[1];
  const float* Umsa = (const float*)d_in[2];

  char* ws = (char*)d_ws;
  _Float16* Ut_qkv = (_Float16*)(ws);
  _Float16* Ut_msa = (_Float16*)(ws + 3538944);
  _Float16* zh = (_Float16*)(ws + 4718592);
  _Float16* Of = zh;  // aliased (zh dead before attn writes Of)
  _Float16* Qf = (_Float16*)(ws + 29884416);
  _Float16* Kf = (_Float16*)(ws + 55050240);
  _Float16* Vt = (_Float16*)(ws + 80216064);

  tconv_kernel<<<dim3(192, 36), 256, 0, stream>>>(Uqkv, Ut_qkv, 768, 64);
  tconv_kernel<<<dim3(2304, 1), 256, 0, stream>>>(Umsa, Ut_msa, 768, 768);
  cvt16_kernel<<<dim3(6144, 1), 256, 0, stream>>>(z, zh, 16384 * 768);

  qkv_gemm_kernel<<<dim3(128, 18), 256, 0, stream>>>(zh, Ut_qkv, Qf, Kf, Vt);
  attn_kernel<<<dim3(1536, 1), 256, 0, stream>>>(Qf, Kf, Vt, Of);
  out_gemm_kernel<<<dim3(128, 6), 256, 0, stream>>>(Of, Ut_msa,
                                                    (float*)d_out);
}